// Round 1
// baseline (4959.221 us; speedup 1.0000x reference)
//
#include <hip/hip_runtime.h>
#include <cstddef>

#define T_STEPS 256
#define NSAT    1024
#define GSAT    2048
#define HID     256
#define IN_DIM  32
#define KTOT    288   // HID + IN_DIM

typedef short  s16x8 __attribute__((ext_vector_type(8)));
typedef float  f32x4 __attribute__((ext_vector_type(4)));
typedef unsigned short ushort_t;

__device__ inline ushort_t f2bf(float f) {
    unsigned u = __builtin_bit_cast(unsigned, f);
    u += 0x7fffu + ((u >> 16) & 1u);
    return (ushort_t)(u >> 16);
}
__device__ inline float sigm(float x) { return 1.f / (1.f + __expf(-x)); }
__device__ inline float tanh_(float x) {
    float a = fabsf(x);
    float e = __expf(-2.f * a);
    float r = (1.f - e) / (1.f + e);
    return copysignf(r, x);
}

// ---------------- init: zero the state region ----------------
__global__ void k_zero(float* p, size_t n) {
    size_t i = (size_t)blockIdx.x * blockDim.x + threadIdx.x;
    size_t stride = (size_t)gridDim.x * blockDim.x;
    for (; i < n; i += stride) p[i] = 0.f;
}

// ---------------- init: build BsatT [1024 cols][288 k] bf16 ----------------
// col c = g*256+o ; k<256 -> r2s_rw[g][k][o] ; k>=256 -> W_sat[g][k-256][o]
__global__ void k_bconv(const float* __restrict__ r2s_rw,
                        const float* __restrict__ W_sat,
                        ushort_t* __restrict__ BsatT) {
    __shared__ ushort_t tile[32][72];
    int k0 = blockIdx.x * 32;   // 0..8 tiles of 32 (288)
    int c0 = blockIdx.y * 64;   // 0..15 tiles of 64 (1024)
    int t  = threadIdx.x;
    int cc = t & 63, kq = (t >> 6) * 8;
#pragma unroll
    for (int j = 0; j < 8; j++) {
        int k = k0 + kq + j;
        int c = c0 + cc;
        int g = c >> 8, o = c & 255;
        float v = (k < 256) ? r2s_rw[((size_t)g * 256 + k) * 256 + o]
                            : W_sat[((size_t)g * 32 + (k - 256)) * 256 + o];
        tile[kq + j][cc] = f2bf(v);
    }
    __syncthreads();
    int cc2 = t >> 2, kq2 = (t & 3) * 8;
    ushort_t v[8];
#pragma unroll
    for (int j = 0; j < 8; j++) v[j] = tile[kq2 + j][cc2];
    ushort_t* dst = BsatT + (size_t)(c0 + cc2) * KTOT + k0 + kq2;
#pragma unroll
    for (int j = 0; j < 8; j++) dst[j] = v[j];
}

// ---------------- per-step satellite kernel ----------------
// grid (8 o-tiles, 32 sat-tiles), 256 threads
__launch_bounds__(256)
__global__ void k_sat(int t,
                      const float* __restrict__ x_sat,
                      const int*   __restrict__ s_ids,
                      const float* __restrict__ r2s_lw,
                      const float* __restrict__ r2s_lb,
                      const float* __restrict__ b_sat,
                      const ushort_t* __restrict__ BsatT,
                      const float* __restrict__ Hg,
                      const float* __restrict__ Cg,
                      float* __restrict__ Hnew,
                      float* __restrict__ Cnew,
                      float* __restrict__ mean_sum,
                      const float* __restrict__ pre_rec,
                      float* __restrict__ crec,
                      float* __restrict__ hrec_g) {
    int bx = blockIdx.x;   // o tile: o in [bx*32, bx*32+32)
    int by = blockIdx.y;   // sat tile: n in [by*32, by*32+32)
    int tid = threadIdx.x;

    __shared__ float hr_s[HID];
    __shared__ float rl_part[2][4][32];
    __shared__ float rl_s[4][32];
    __shared__ int   sid_s[32];
    __shared__ float pre_s[32][129];

    // ---- P0: receiver update for step t-1 (redundant per block) ----
    {
        int o = tid;
        float h, c;
        if (t == 0) { h = 0.f; c = 0.f; }
        else {
            const float* pr = pre_rec + (size_t)(t - 1) * 1024;
            float p0 = pr[o], p1 = pr[256 + o], p2 = pr[512 + o], p3 = pr[768 + o];
            float cp = (t >= 2) ? crec[(size_t)(t - 2) * 256 + o] : 0.f;
            float ig = sigm(p0), fg = sigm(p1), tg = tanh_(p2), og = sigm(p3);
            c = fg * cp + ig * tg;
            h = og * tanh_(c);
        }
        hr_s[o] = h;
        if (bx == 0 && by == 0) {
            if (t >= 1) crec[(size_t)(t - 1) * 256 + o] = 0.f, crec[(size_t)(t - 1) * 256 + o] = ([&]{ return 0.f; }(), 0.f);
        }
        // (real writes below, after recompute to keep it simple)
        if (bx == 0 && by == 0) {
            if (t >= 1) {
                // recompute c to store (cheap)
                const float* pr = pre_rec + (size_t)(t - 1) * 1024;
                float p0 = pr[o], p1 = pr[256 + o], p2 = pr[512 + o], p3 = pr[768 + o];
                float cp = (t >= 2) ? crec[(size_t)(t - 2) * 256 + o] : 0.f;
                float ig = sigm(p0), fg = sigm(p1), tg = tanh_(p2);
                crec[(size_t)(t - 1) * 256 + o] = fg * cp + ig * tg;
            }
            hrec_g[o] = h;
        }
    }
    if (tid < 32) sid_s[tid] = s_ids[(size_t)t * NSAT + by * 32 + tid];
    __syncthreads();

    // ---- P0b: rl slice = h_rec @ r2s_lw[:, :, o-slice] + r2s_lb ----
    {
        int hh = tid >> 7;           // 0..1 (h halves)
        int rem = tid & 127;
        int g = rem >> 5, ol = rem & 31;
        const float* wp = r2s_lw + ((size_t)g * 256 + hh * 128) * 256 + bx * 32 + ol;
        float acc = 0.f;
#pragma unroll 4
        for (int h = 0; h < 128; h++) acc += hr_s[hh * 128 + h] * wp[(size_t)h * 256];
        rl_part[hh][g][ol] = acc;
    }
    __syncthreads();
    if (tid < 128) {
        int g = tid >> 5, ol = tid & 31;
        rl_s[g][ol] = rl_part[0][g][ol] + rl_part[1][g][ol]
                    + r2s_lb[g * 256 + bx * 32 + ol];
    }
    // ---- P1: mean partial (col-block 0 only; Hg is read-only this kernel) ----
    if (bx == 0) {
        int k = tid;
        float s = 0.f;
#pragma unroll 4
        for (int n = 0; n < 32; n++) s += Hg[(size_t)sid_s[n] * HID + k];
        atomicAdd(&mean_sum[(size_t)t * HID + k], s);
    }
    __syncthreads();

    // ---- P2: MFMA GEMM: C[32 sats][128 gcols], K=288 ----
    int w = tid >> 6, l = tid & 63;
    int rt = w & 1;                  // row frag 0/1
    int cfb = (w >> 1) * 4;          // col-frag base (4 frags per wave)
    int row_l = rt * 16 + (l & 15);
    int kb = (l >> 4) * 8;
    int sidr = sid_s[row_l];
    const float* arow_h = Hg + (size_t)sidr * HID;
    const float* arow_x = x_sat + ((size_t)t * NSAT + by * 32 + row_l) * IN_DIM;

    f32x4 acc[4];
#pragma unroll
    for (int q = 0; q < 4; q++) acc[q] = (f32x4){0.f, 0.f, 0.f, 0.f};

    size_t brow[4];
#pragma unroll
    for (int q = 0; q < 4; q++) {
        int c = (cfb + q) * 16 + (l & 15);
        int g = c >> 5, ol = c & 31;
        brow[q] = ((size_t)(g * 256 + bx * 32 + ol)) * KTOT;
    }

    for (int kc = 0; kc < 9; kc++) {
        int k0 = kc * 32 + kb;
        const float* ap = (kc < 8) ? (arow_h + k0) : (arow_x + kb);
        f32x4 f0 = *(const f32x4*)ap;
        f32x4 f1 = *(const f32x4*)(ap + 4);
        s16x8 af;
#pragma unroll
        for (int j = 0; j < 4; j++) af[j] = (short)f2bf(f0[j]);
#pragma unroll
        for (int j = 0; j < 4; j++) af[4 + j] = (short)f2bf(f1[j]);
#pragma unroll
        for (int q = 0; q < 4; q++) {
            s16x8 bf = *(const s16x8*)(BsatT + brow[q] + k0);
            acc[q] = __builtin_amdgcn_mfma_f32_16x16x32_bf16(af, bf, acc[q], 0, 0, 0);
        }
    }

    // ---- P3: epilogue — regroup gates via LDS, LSTM, write Hnew/Cnew ----
#pragma unroll
    for (int q = 0; q < 4; q++) {
        int cbase = (cfb + q) * 16 + (l & 15);
#pragma unroll
        for (int r = 0; r < 4; r++)
            pre_s[rt * 16 + (l >> 4) * 4 + r][cbase] = acc[q][r];
    }
    __syncthreads();
#pragma unroll
    for (int p = 0; p < 4; p++) {
        int idx = tid + p * 256;
        int n = idx >> 5;
        int ol = idx & 31;
        int og_ = bx * 32 + ol;
        float p0 = pre_s[n][0 * 32 + ol] + rl_s[0][ol] + b_sat[0 * 256 + og_];
        float p1 = pre_s[n][1 * 32 + ol] + rl_s[1][ol] + b_sat[1 * 256 + og_];
        float p2 = pre_s[n][2 * 32 + ol] + rl_s[2][ol] + b_sat[2 * 256 + og_];
        float p3 = pre_s[n][3 * 32 + ol] + rl_s[3][ol] + b_sat[3 * 256 + og_];
        float ig = sigm(p0), fg = sigm(p1), tg = tanh_(p2), oo = sigm(p3);
        float co = Cg[(size_t)sid_s[n] * HID + og_];
        float cn = fg * co + ig * tg;
        float hn = oo * tanh_(cn);
        size_t wo = ((size_t)(by * 32 + n)) * HID + og_;
        Hnew[wo] = hn;
        Cnew[wo] = cn;
    }
}

// ---------------- per-step receiver/scatter kernel ----------------
// blocks 0..63: scatter Hnew/Cnew -> Hg/Cg (16 rows each)
// blocks 64..95: s2r conv partials (8 h each) -> atomicAdd pre_rec[t]
// blocks 96..99: x_rec projection partials (8 i each); block 96 adds biases
__global__ void k_rec(int t,
                      const float* __restrict__ x_rec,
                      const int*   __restrict__ s_ids,
                      const float* __restrict__ W_rec,
                      const float* __restrict__ b_rec,
                      const float* __restrict__ s2r_lw,
                      const float* __restrict__ s2r_lb,
                      const float* __restrict__ s2r_rw,
                      const float* __restrict__ Hnew,
                      const float* __restrict__ Cnew,
                      float* __restrict__ Hg,
                      float* __restrict__ Cg,
                      const float* __restrict__ mean_sum,
                      const float* __restrict__ hrec_g,
                      float* __restrict__ pre_rec) {
    int b = blockIdx.x, tid = threadIdx.x;
    if (b < 64) {
        for (int i = 0; i < 16; i++) {
            int n = b * 16 + i;
            int j = s_ids[(size_t)t * NSAT + n];
            Hg[(size_t)j * HID + tid] = Hnew[(size_t)n * HID + tid];
            Cg[(size_t)j * HID + tid] = Cnew[(size_t)n * HID + tid];
        }
    } else if (b < 96) {
        int h0 = (b - 64) * 8;
        int o = tid;
        float acc[4] = {0.f, 0.f, 0.f, 0.f};
        for (int h = 0; h < 8; h++) {
            float m = mean_sum[(size_t)t * HID + h0 + h] * (1.f / 1024.f);
            float r = hrec_g[h0 + h];
#pragma unroll
            for (int g = 0; g < 4; g++) {
                acc[g] += m * s2r_lw[((size_t)g * 256 + h0 + h) * 256 + o]
                        + r * s2r_rw[((size_t)g * 256 + h0 + h) * 256 + o];
            }
        }
#pragma unroll
        for (int g = 0; g < 4; g++)
            atomicAdd(&pre_rec[(size_t)t * 1024 + g * 256 + o], acc[g]);
    } else {
        int i0 = (b - 96) * 8;
        int o = tid;
        float acc[4] = {0.f, 0.f, 0.f, 0.f};
        for (int i = 0; i < 8; i++) {
            float x = x_rec[(size_t)t * IN_DIM + i0 + i];
#pragma unroll
            for (int g = 0; g < 4; g++)
                acc[g] += x * W_rec[((size_t)g * IN_DIM + i0 + i) * HID + o];
        }
        if (b == 96) {
#pragma unroll
            for (int g = 0; g < 4; g++)
                acc[g] += b_rec[g * HID + o] + s2r_lb[g * HID + o];
        }
#pragma unroll
        for (int g = 0; g < 4; g++)
            atomicAdd(&pre_rec[(size_t)t * 1024 + g * 256 + o], acc[g]);
    }
}

// ---------------- final: receiver update 255 + output proj ----------------
__global__ void k_final(const float* __restrict__ pre_rec,
                        const float* __restrict__ crec,
                        const float* __restrict__ W_out,
                        const float* __restrict__ b_out,
                        const float* __restrict__ y_true,
                        float* __restrict__ out) {
    __shared__ float hr[256];
    __shared__ float red[256];
    int o = threadIdx.x;
    const float* pr = pre_rec + (size_t)255 * 1024;
    float p0 = pr[o], p1 = pr[256 + o], p2 = pr[512 + o], p3 = pr[768 + o];
    float cp = crec[(size_t)254 * 256 + o];
    float ig = sigm(p0), fg = sigm(p1), tg = tanh_(p2), og = sigm(p3);
    float c = fg * cp + ig * tg;
    float h = og * tanh_(c);
    hr[o] = h;
    __syncthreads();
    for (int j = 0; j < 2; j++) {
        float v = hr[o] * W_out[o * 2 + j];
        red[o] = v;
        __syncthreads();
        for (int s = 128; s > 0; s >>= 1) {
            if (o < s) red[o] += red[o + s];
            __syncthreads();
        }
        if (o == 0) out[j] = red[0] + b_out[j];
        __syncthreads();
    }
    if (o < 2) out[2 + o] = y_true[o];
}

extern "C" void kernel_launch(void* const* d_in, const int* in_sizes, int n_in,
                              void* d_out, int out_size, void* d_ws, size_t ws_size,
                              hipStream_t stream) {
    (void)in_sizes; (void)n_in; (void)out_size; (void)ws_size;
    const float* x_rec  = (const float*)d_in[0];
    const float* x_sat  = (const float*)d_in[1];
    const float* y_true = (const float*)d_in[2];
    const float* W_rec  = (const float*)d_in[3];
    const float* b_rec  = (const float*)d_in[4];
    const float* W_sat  = (const float*)d_in[5];
    const float* b_sat  = (const float*)d_in[6];
    const float* s2r_lw = (const float*)d_in[7];
    const float* s2r_lb = (const float*)d_in[8];
    const float* s2r_rw = (const float*)d_in[9];
    const float* r2s_lw = (const float*)d_in[10];
    const float* r2s_lb = (const float*)d_in[11];
    const float* r2s_rw = (const float*)d_in[12];
    const float* W_out  = (const float*)d_in[13];
    const float* b_out  = (const float*)d_in[14];
    const int*   s_ids  = (const int*)d_in[15];

    float* ws = (float*)d_ws;
    float* Hg       = ws;                    // 2048*256
    float* Cg       = Hg + 524288;           // 2048*256
    float* mean_sum = Cg + 524288;           // 256*256
    float* pre_rec  = mean_sum + 65536;      // 256*4*256
    float* crec     = pre_rec + 262144;      // 256*256
    float* hrec_g   = crec + 65536;          // 256
    float* Hnew     = hrec_g + 256;          // 1024*256
    float* Cnew     = Hnew + 262144;         // 1024*256
    ushort_t* BsatT = (ushort_t*)(Cnew + 262144); // 1024*288 bf16

    const size_t zcount = 524288ull * 2 + 65536 + 262144 + 65536 + 256;
    hipLaunchKernelGGL(k_zero, dim3(2048), dim3(256), 0, stream, ws, zcount);
    hipLaunchKernelGGL(k_bconv, dim3(9, 16), dim3(256), 0, stream, r2s_rw, W_sat, BsatT);

    for (int t = 0; t < T_STEPS; t++) {
        hipLaunchKernelGGL(k_sat, dim3(8, 32), dim3(256), 0, stream,
                           t, x_sat, s_ids, r2s_lw, r2s_lb, b_sat, BsatT,
                           Hg, Cg, Hnew, Cnew, mean_sum, pre_rec, crec, hrec_g);
        hipLaunchKernelGGL(k_rec, dim3(100), dim3(256), 0, stream,
                           t, x_rec, s_ids, W_rec, b_rec, s2r_lw, s2r_lb, s2r_rw,
                           Hnew, Cnew, Hg, Cg, mean_sum, hrec_g, pre_rec);
    }
    hipLaunchKernelGGL(k_final, dim3(1), dim3(256), 0, stream,
                       pre_rec, crec, W_out, b_out, y_true, (float*)d_out);
}